// Round 5
// baseline (449.354 us; speedup 1.0000x reference)
//
#include <hip/hip_runtime.h>
#include <cstdint>

#define B_ 64
#define M_ 1024
#define E_ 256
#define NW_ 32000
#define PL_ 128

// output element offsets (fp32 elements)
#define P_OFF   0
#define PV_OFF  65536
#define PR_OFF  2113536
#define H_OFF   2179072

typedef unsigned short u16;
typedef unsigned int u32;

typedef __bf16 bf16x8 __attribute__((ext_vector_type(8)));
typedef float f32x4 __attribute__((ext_vector_type(4)));

__device__ __forceinline__ u16 f2bf(float f) {
    u32 x = __builtin_bit_cast(u32, f);
    return (u16)((x + 0x7fffu + ((x >> 16) & 1u)) >> 16);
}
__device__ __forceinline__ bf16x8 pack8f(const float* v) {
    union { u16 s[8]; bf16x8 b; } u;
#pragma unroll
    for (int j = 0; j < 8; j++) u.s[j] = f2bf(v[j]);
    return u.b;
}
__device__ __forceinline__ bf16x8 pack_bf8(float4 a, float4 b) {
    float v[8] = {a.x, a.y, a.z, a.w, b.x, b.y, b.z, b.w};
    return pack8f(v);
}

// ---------------------------------------------------------------------------
// K1: GRU step + profile encoding.  64 blocks x 256 threads.
// ---------------------------------------------------------------------------
__global__ __launch_bounds__(256) void k_gru(
    const float* __restrict__ tables, const float* __restrict__ Wih,
    const float* __restrict__ Whh, const float* __restrict__ bih,
    const float* __restrict__ bhh, const float* __restrict__ Wp,
    const float* __restrict__ bp, const int* __restrict__ y,
    const float* __restrict__ h_, const float* __restrict__ pe,
    float* __restrict__ q0, float* __restrict__ enc, float* __restrict__ outh)
{
    int b = blockIdx.x, t = threadIdx.x;
    __shared__ float m_s[E_], h_s[E_], pe_s[PL_];
    int yb = y[b];
    m_s[t] = tables[(size_t)NW_ * E_ + (size_t)yb * E_ + t];  // row 0 is zero
    h_s[t] = h_[b * E_ + t];
    if (t < PL_) pe_s[t] = pe[b * PL_ + t];
    __syncthreads();

    float g_i[3], g_h[3];
#pragma unroll
    for (int g = 0; g < 3; g++) {
        int j = g * E_ + t;
        float ai = bih[j], ah = bhh[j];
        const float4* wi = (const float4*)(Wih + (size_t)j * E_);
        const float4* wh = (const float4*)(Whh + (size_t)j * E_);
#pragma unroll 8
        for (int e = 0; e < E_ / 4; e++) {
            float4 a = wi[e], c = wh[e];
            ai += a.x * m_s[4 * e] + a.y * m_s[4 * e + 1] +
                  a.z * m_s[4 * e + 2] + a.w * m_s[4 * e + 3];
            ah += c.x * h_s[4 * e] + c.y * h_s[4 * e + 1] +
                  c.z * h_s[4 * e + 2] + c.w * h_s[4 * e + 3];
        }
        g_i[g] = ai; g_h[g] = ah;
    }
    float r = 1.f / (1.f + expf(-(g_i[0] + g_h[0])));
    float z = 1.f / (1.f + expf(-(g_i[1] + g_h[1])));
    float n = tanhf(g_i[2] + r * g_h[2]);
    float hv = (1.f - z) * n + z * h_s[t];
    q0[b * E_ + t] = hv;
    outh[b * E_ + t] = hv;

    float ea = bp[t];
    const float4* wp = (const float4*)(Wp + (size_t)t * PL_);
#pragma unroll 8
    for (int p = 0; p < PL_ / 4; p++) {
        float4 a = wp[p];
        ea += a.x * pe_s[4 * p] + a.y * pe_s[4 * p + 1] +
              a.z * pe_s[4 * p + 2] + a.w * pe_s[4 * p + 3];
    }
    enc[b * E_ + t] = ea;
}

// ---------------------------------------------------------------------------
// K2: D = tab @ Q^T  via MFMA.  D[idx][NB], Q is NB rows x 256.
// NB=64: grid 125, wave = 4 m-frags; NB=128: grid 250, wave = 2 m-frags.
// ZERO: also zero the 2,048,000-float wz buffer (next hop's scatter target).
// ---------------------------------------------------------------------------
template <int NB, bool ZERO>
__global__ __launch_bounds__(256) void k_dgemm(
    const float* __restrict__ tab, const float* __restrict__ Q,
    float* __restrict__ D, float* __restrict__ wz)
{
    constexpr int MT = (NB == 128) ? 2 : 4;
    constexpr int NT = NB / 16;
    int tid = threadIdx.x, lane = tid & 63, w = tid >> 6;
    int l15 = lane & 15, quad = lane >> 4;
    int blk = blockIdx.x;
    int m0 = blk * (MT * 64) + w * (MT * 16);

    if (ZERO) {
        int id = blk * 256 + tid;
        constexpr int per4 = (NB == 128) ? 8 : 16;  // float4s per thread
        float4 z = make_float4(0.f, 0.f, 0.f, 0.f);
        float4* p = (float4*)wz + (size_t)id * per4;
#pragma unroll
        for (int i = 0; i < per4; i++) p[i] = z;
    }

    f32x4 acc[MT][NT];
#pragma unroll
    for (int mt = 0; mt < MT; mt++)
#pragma unroll
        for (int nt = 0; nt < NT; nt++) acc[mt][nt] = f32x4{0.f, 0.f, 0.f, 0.f};

#pragma unroll
    for (int ks = 0; ks < 8; ks++) {
        int k0 = ks * 32 + quad * 8;
        bf16x8 a[MT], bb[NT];
#pragma unroll
        for (int mt = 0; mt < MT; mt++) {
            const float* s = tab + (size_t)(m0 + mt * 16 + l15) * E_ + k0;
            a[mt] = pack_bf8(*(const float4*)s, *(const float4*)(s + 4));
        }
#pragma unroll
        for (int nt = 0; nt < NT; nt++) {
            const float* s = Q + (size_t)(nt * 16 + l15) * E_ + k0;
            bb[nt] = pack_bf8(*(const float4*)s, *(const float4*)(s + 4));
        }
#pragma unroll
        for (int mt = 0; mt < MT; mt++)
#pragma unroll
            for (int nt = 0; nt < NT; nt++)
                acc[mt][nt] = __builtin_amdgcn_mfma_f32_16x16x32_bf16(
                    a[mt], bb[nt], acc[mt][nt], 0, 0, 0);
    }
#pragma unroll
    for (int mt = 0; mt < MT; mt++)
#pragma unroll
        for (int nt = 0; nt < NT; nt++)
#pragma unroll
            for (int j = 0; j < 4; j++) {
                int idx = m0 + mt * 16 + quad * 4 + j;
                D[(size_t)idx * NB + nt * 16 + l15] = acc[mt][nt][j];
            }
}

// ---------------------------------------------------------------------------
// K3: per-hop gather of D + softmax + scatter attn into wT (fp32 atomics).
// MODE 0: D stride 64, softmax+scatter.  MODE 1: D stride 128 (D1 | DR),
// also write p_resto.  MODE 2: D stride 64, write p only.
// grid 64 (one b per block) x 1024 threads (one m each).
// ---------------------------------------------------------------------------
template <int MODE>
__global__ __launch_bounds__(1024) void k_hop(
    const float* __restrict__ D, const int* __restrict__ ctx,
    float* __restrict__ wT, float* __restrict__ out)
{
    int b = blockIdx.x, m = threadIdx.x;
    int4 c = *(const int4*)(ctx + ((size_t)b * M_ + m) * 4);
    float v;
    if (MODE == 1) {
        v = D[(size_t)c.x * 128 + b] + D[(size_t)c.y * 128 + b] +
            D[(size_t)c.z * 128 + b] + D[(size_t)c.w * 128 + b];
        float vr = D[(size_t)c.x * 128 + 64 + b] + D[(size_t)c.y * 128 + 64 + b] +
                   D[(size_t)c.z * 128 + 64 + b] + D[(size_t)c.w * 128 + 64 + b];
        out[PR_OFF + (size_t)b * M_ + m] = vr;
    } else {
        v = D[(size_t)c.x * 64 + b] + D[(size_t)c.y * 64 + b] +
            D[(size_t)c.z * 64 + b] + D[(size_t)c.w * 64 + b];
    }
    if (MODE == 2) {
        out[P_OFF + (size_t)b * M_ + m] = v;
        return;
    }
    // block-wide softmax over 1024 m
    __shared__ float red[32];
    int lane = m & 63, wid = m >> 6;
    float mx = v;
#pragma unroll
    for (int o = 32; o > 0; o >>= 1) mx = fmaxf(mx, __shfl_xor(mx, o, 64));
    if (lane == 0) red[wid] = mx;
    __syncthreads();
    mx = red[0];
#pragma unroll
    for (int k = 1; k < 16; k++) mx = fmaxf(mx, red[k]);
    float e = expf(v - mx), s = e;
#pragma unroll
    for (int o = 32; o > 0; o >>= 1) s += __shfl_xor(s, o, 64);
    if (lane == 0) red[16 + wid] = s;
    __syncthreads();
    s = 0.f;
#pragma unroll
    for (int k = 0; k < 16; k++) s += red[16 + k];
    float a = e / s;
    float* row = wT + (size_t)b * NW_;
    atomicAdd(row + c.x, a);
    atomicAdd(row + c.y, a);
    atomicAdd(row + c.z, a);
    atomicAdd(row + c.w, a);
}

// ---------------------------------------------------------------------------
// K4: O^T[b][e] = sum_idx wT[b][idx] * tab[idx][e]  (K split over 125 blocks,
// 256 idx each).  Writes partials part[blk][64][256].
// wave w covers e-range w*64..w*64+64 (4 n-frags), all 64 b (4 m-frags).
// ---------------------------------------------------------------------------
__global__ __launch_bounds__(256) void k_ogemm(
    const float* __restrict__ tab, const float* __restrict__ wT,
    float* __restrict__ part)
{
    int tid = threadIdx.x, lane = tid & 63, w = tid >> 6;
    int l15 = lane & 15, quad = lane >> 4;
    int blk = blockIdx.x;
    int kbase = blk * 256;

    f32x4 acc[4][4];
#pragma unroll
    for (int mt = 0; mt < 4; mt++)
#pragma unroll
        for (int nt = 0; nt < 4; nt++) acc[mt][nt] = f32x4{0.f, 0.f, 0.f, 0.f};

#pragma unroll 2
    for (int ks = 0; ks < 8; ks++) {
        int k0 = kbase + ks * 32 + quad * 8;
        bf16x8 a[4], bb[4];
#pragma unroll
        for (int mt = 0; mt < 4; mt++) {
            const float* s = wT + (size_t)(mt * 16 + l15) * NW_ + k0;
            a[mt] = pack_bf8(*(const float4*)s, *(const float4*)(s + 4));
        }
#pragma unroll
        for (int nt = 0; nt < 4; nt++) {
            int e = w * 64 + nt * 16 + l15;
            float v[8];
#pragma unroll
            for (int j = 0; j < 8; j++) v[j] = tab[(size_t)(k0 + j) * E_ + e];
            bb[nt] = pack8f(v);
        }
#pragma unroll
        for (int mt = 0; mt < 4; mt++)
#pragma unroll
            for (int nt = 0; nt < 4; nt++)
                acc[mt][nt] = __builtin_amdgcn_mfma_f32_16x16x32_bf16(
                    a[mt], bb[nt], acc[mt][nt], 0, 0, 0);
    }
#pragma unroll
    for (int mt = 0; mt < 4; mt++)
#pragma unroll
        for (int nt = 0; nt < 4; nt++)
#pragma unroll
            for (int j = 0; j < 4; j++) {
                int bb_ = mt * 16 + quad * 4 + j;
                int e = w * 64 + nt * 16 + l15;
                part[(size_t)blk * 16384 + bb_ * 256 + e] = acc[mt][nt][j];
            }
}

// ---------------------------------------------------------------------------
// K5: q_out = q_prev + sum_blk part;  optionally qe = q_out * enc.
// grid 64 x 256.
// ---------------------------------------------------------------------------
template <bool HAS_ENC>
__global__ __launch_bounds__(256) void k_qup(
    const float* __restrict__ part, const float* __restrict__ qprev,
    const float* __restrict__ enc, float* __restrict__ qout,
    float* __restrict__ qe)
{
    int b = blockIdx.x, t = threadIdx.x;
    const float* p = part + b * E_ + t;
    float s0 = 0.f, s1 = 0.f, s2 = 0.f, s3 = 0.f;
    int i = 0;
    for (; i + 4 <= 125; i += 4) {
        s0 += p[(size_t)(i + 0) * 16384];
        s1 += p[(size_t)(i + 1) * 16384];
        s2 += p[(size_t)(i + 2) * 16384];
        s3 += p[(size_t)(i + 3) * 16384];
    }
    for (; i < 125; i++) s0 += p[(size_t)i * 16384];
    float s = qprev[b * E_ + t] + s0 + s1 + s2 + s3;
    qout[b * E_ + t] = s;
    if (HAS_ENC) qe[b * E_ + t] = s * enc[b * E_ + t];
}

// ---------------------------------------------------------------------------
// K6: p_vocab = [h ; o0] @ Wv^T + bv via MFMA 16x16x32 bf16.
// ---------------------------------------------------------------------------
__global__ __launch_bounds__(256) void k_pvocab(
    const float* __restrict__ Wv, const float* __restrict__ bv,
    const float* __restrict__ q0, const float* __restrict__ q1,
    float* __restrict__ out)
{
    __shared__ u16 X[64 * 512];  // 64KB
    int t = threadIdx.x;
#pragma unroll
    for (int it = 0; it < 16; it++) {
        int id = t + it * 256;
        int bb = id >> 6, c = id & 63;
        float v[8];
        if (c < 32) {
            const float* s = q0 + bb * E_ + c * 8;
#pragma unroll
            for (int j = 0; j < 8; j++) v[j] = s[j];
        } else {
            const float* s1 = q1 + bb * E_ + (c - 32) * 8;
            const float* s0 = q0 + bb * E_ + (c - 32) * 8;
#pragma unroll
            for (int j = 0; j < 8; j++) v[j] = s1[j] - s0[j];
        }
        union { u16 s[8]; uint4 u; } pk;
#pragma unroll
        for (int j = 0; j < 8; j++) pk.s[j] = f2bf(v[j]);
        *(uint4*)(&X[bb * 512 + ((c ^ (bb & 7)) << 3)]) = pk.u;
    }
    __syncthreads();

    int lane = t & 63, w = t >> 6;
    int n0 = blockIdx.x * 128 + w * 32;
    int l15 = lane & 15, quad = lane >> 4;
    f32x4 acc[4][2];
#pragma unroll
    for (int mt = 0; mt < 4; mt++)
#pragma unroll
        for (int nt = 0; nt < 2; nt++) acc[mt][nt] = f32x4{0.f, 0.f, 0.f, 0.f};

    for (int ks = 0; ks < 16; ks++) {
        bf16x8 a[4], bfr[2];
#pragma unroll
        for (int mt = 0; mt < 4; mt++) {
            int m = mt * 16 + l15;
            int c = ks * 4 + quad;
            a[mt] = *(const bf16x8*)(&X[m * 512 + ((c ^ (m & 7)) << 3)]);
        }
#pragma unroll
        for (int nt = 0; nt < 2; nt++) {
            int n = n0 + nt * 16 + l15;
            const float4* wp = (const float4*)(Wv + (size_t)n * 512 + ks * 32 + quad * 8);
            bfr[nt] = pack_bf8(wp[0], wp[1]);
        }
#pragma unroll
        for (int mt = 0; mt < 4; mt++)
#pragma unroll
            for (int nt = 0; nt < 2; nt++)
                acc[mt][nt] = __builtin_amdgcn_mfma_f32_16x16x32_bf16(
                    a[mt], bfr[nt], acc[mt][nt], 0, 0, 0);
    }
#pragma unroll
    for (int nt = 0; nt < 2; nt++) {
        int n = n0 + nt * 16 + l15;
        float bvv = bv[n];
#pragma unroll
        for (int mt = 0; mt < 4; mt++) {
#pragma unroll
            for (int j = 0; j < 4; j++) {
                int m = mt * 16 + quad * 4 + j;
                out[PV_OFF + (size_t)m * 32000 + n] = acc[mt][nt][j] + bvv;
            }
        }
    }
}

// ---------------------------------------------------------------------------
extern "C" void kernel_launch(void* const* d_in, const int* in_sizes, int n_in,
                              void* d_out, int out_size, void* d_ws, size_t ws_size,
                              hipStream_t stream)
{
    const float* tables = (const float*)d_in[0];
    const float* Wih = (const float*)d_in[1];
    const float* Whh = (const float*)d_in[2];
    const float* bih = (const float*)d_in[3];
    const float* bhh = (const float*)d_in[4];
    const float* Wp  = (const float*)d_in[5];
    const float* bp  = (const float*)d_in[6];
    const float* Wv  = (const float*)d_in[7];
    const float* bv  = (const float*)d_in[8];
    const int* ctx = (const int*)d_in[9];
    const int* y   = (const int*)d_in[10];
    const float* h_  = (const float*)d_in[11];
    const float* pe  = (const float*)d_in[12];
    float* out = (float*)d_out;

    // ws layout (floats)
    float* Wf  = (float*)d_ws;
    float* q0  = Wf;                 // 16384
    float* q1  = Wf + 16384;         // 16384  (q1e must follow contiguously!)
    float* q1e = Wf + 32768;         // 16384
    float* q2  = Wf + 49152;         // 16384
    float* enc = Wf + 65536;         // 16384
    float* wT1 = Wf + 81920;         // 2,048,000
    float* wT2 = wT1 + 2048000;      // 2,048,000
    float* D0  = wT2 + 2048000;      // 2,048,000
    float* D1R = D0 + 2048000;       // 4,096,000
    float* D2  = D1R + 4096000;      // 2,048,000
    float* part= D2 + 2048000;       // 2,048,000

    const size_t TSZ = (size_t)NW_ * E_;
    const float* t0 = tables;
    const float* t1 = tables + TSZ;
    const float* t2 = tables + 2 * TSZ;

    k_gru<<<64, 256, 0, stream>>>(tables, Wih, Whh, bih, bhh, Wp, bp, y, h_, pe,
                                  q0, enc, out + H_OFF);
    // hop 0: D0 = t0 @ q0^T (also zero wT1), gather+softmax+scatter
    k_dgemm<64, true><<<125, 256, 0, stream>>>(t0, q0, D0, wT1);
    k_hop<0><<<64, 1024, 0, stream>>>(D0, ctx, wT1, out);
    // o0 = t1^T @ wT1 ; q1 = q0 + o0 ; q1e = q1*enc
    k_ogemm<<<125, 256, 0, stream>>>(t1, wT1, part);
    k_qup<true><<<64, 256, 0, stream>>>(part, q0, enc, q1, q1e);
    // hop 1: D1R = t1 @ [q1;q1e]^T (also zero wT2); gather (+p_resto), scatter
    k_dgemm<128, true><<<250, 256, 0, stream>>>(t1, q1, D1R, wT2);
    k_hop<1><<<64, 1024, 0, stream>>>(D1R, ctx, wT2, out);
    // o1 = t2^T @ wT2 ; q2 = q1 + o1
    k_ogemm<<<125, 256, 0, stream>>>(t2, wT2, part);
    k_qup<false><<<64, 256, 0, stream>>>(part, q1, enc, q2, nullptr);
    // hop 2: D2 = t2 @ q2^T ; p out
    k_dgemm<64, false><<<125, 256, 0, stream>>>(t2, q2, D2, nullptr);
    k_hop<2><<<64, 1024, 0, stream>>>(D2, ctx, nullptr, out);
    // p_vocab head
    k_pvocab<<<250, 256, 0, stream>>>(Wv, bv, q0, q1, out);
}